// Round 1
// baseline (1165.444 us; speedup 1.0000x reference)
//
#include <hip/hip_runtime.h>

// FirstOrderCondRNN: B=48 batches, n_kc=800, n_mbon=n_dan=20, n_fbn=60,
// n_recur=100, T=121 (120 steps). One block per batch item; W/wt state in
// registers; r-dynamics via LDS; all outputs streamed per step.

#define NB   48
#define NK   800
#define NM   20
#define NF   60
#define NE   2
#define TT   121
#define NR   100
#define ND   20
#define NSTEP 120

#define R_OFF   0
#define W_OFF   580800      // 121*48*100
#define WT_OFF  93508800    // + 121*48*20*800
#define RO_OFF  186436800   // + 121*48*20*800

__global__ __launch_bounds__(640)
void rnn_step_kernel(const float* __restrict__ r_kc,
                     const float* __restrict__ r_ext,
                     const float* __restrict__ timev,
                     const float* __restrict__ W_kc0,
                     const float* __restrict__ wt0,
                     const float* __restrict__ W_recur,
                     const float* __restrict__ W_readout,
                     const float* __restrict__ bias,
                     const float* __restrict__ W_ext,
                     float* __restrict__ out)
{
    const int b   = blockIdx.x;
    const int tid = threadIdx.x;
    const int d   = tid >> 5;   // 0..19 (row of W for this thread)
    const int kg  = tid & 31;   // 0..31 (column group)

    __shared__ __align__(16) float Wr_sh[NR * NR];   // 40 KB, DAN cols zeroed
    __shared__ __align__(16) float rkc_sh[NK];
    __shared__ __align__(16) float vsh[NK];          // rb_kc trace
    __shared__ float rsh[NR];
    __shared__ float rnew_sh[NR];
    __shared__ float bias_sh[NR];
    __shared__ float Imbon_sh[NM];
    __shared__ float rbdan_sh[ND];
    __shared__ float rdan_sh[ND];
    __shared__ float Wro_sh[NM];

    const float dt  = timev[1] - timev[0];   // 0.5
    const float dtw = dt * 0.2f;             // dt / TAU_W
    const float dtr = dt;                    // dt / TAU_R (TAU_R = 1)

    // ---- init: stage Wr (with [:NM, -ND:] = 0 patch), bias, readout ----
    for (int idx = tid; idx < NR * NR; idx += 640) {
        int i = idx / NR, j = idx - i * NR;
        float w = W_recur[idx];
        if (i < NM && j >= NR - ND) w = 0.f;
        Wr_sh[idx] = w;
    }
    if (tid < NR) {
        bias_sh[tid] = bias[tid];
        float r0 = (tid < NM) ? 0.f : 0.1f;
        rsh[tid] = r0;
        out[R_OFF + (size_t)b * NR + tid] = r0;   // r_all[0]
    }
    if (tid < NM) { Wro_sh[tid] = W_readout[tid]; rbdan_sh[tid] = 0.1f; }
    if (tid == 0) out[RO_OFF + b] = 0.f;          // ro_all[0] (r0 mbon = 0)

    // ---- load W/wt state into registers; write t=0 history slices ----
    float4 Wv[7], wtv[7], uv[7];
    const size_t rowbase = ((size_t)b * NM + d) * NK;
    #pragma unroll
    for (int j = 0; j < 7; ++j) {
        int k0 = 4 * kg + 128 * j;
        if (k0 < NK) {
            Wv[j]  = *(const float4*)(W_kc0 + rowbase + k0);
            wtv[j] = *(const float4*)(wt0   + rowbase + k0);
            *(float4*)(out + W_OFF  + rowbase + k0) = Wv[j];
            *(float4*)(out + WT_OFF + rowbase + k0) = wtv[j];
        }
    }
    __syncthreads();

    for (int t = 0; t < NSTEP; ++t) {
        // S0: stage rkc column (strided input: t innermost), update rb_kc
        for (int k = tid; k < NK; k += 640) {
            float u = r_kc[((size_t)b * NK + k) * TT + t];
            rkc_sh[k] = u;
            float vold = (t == 0) ? u : vsh[k];
            vsh[k] = vold + (u - vold) * dtw;
        }
        __syncthreads();

        // S1: I_mbon = sum_k W[d,k]*u[k]  (per-thread dot + 32-lane butterfly)
        float partial = 0.f;
        #pragma unroll
        for (int j = 0; j < 7; ++j) {
            int k0 = 4 * kg + 128 * j;
            if (k0 < NK) {
                uv[j] = *(const float4*)&rkc_sh[k0];
                partial += Wv[j].x * uv[j].x + Wv[j].y * uv[j].y
                         + Wv[j].z * uv[j].z + Wv[j].w * uv[j].w;
            }
        }
        partial += __shfl_xor(partial, 1);
        partial += __shfl_xor(partial, 2);
        partial += __shfl_xor(partial, 4);
        partial += __shfl_xor(partial, 8);
        partial += __shfl_xor(partial, 16);
        if (kg == 0) Imbon_sh[d] = partial;

        // Wr_prod[i] = sum_j r[j]*Wr[i,j], 4 lanes per row
        float wp = 0.f;
        if (tid < 4 * NR) {
            int i = tid >> 2, jg = tid & 3;
            const float* wr = Wr_sh + i * NR + jg * 25;
            const float* rr = rsh + jg * 25;
            #pragma unroll
            for (int j = 0; j < 25; ++j) wp += rr[j] * wr[j];
            wp += __shfl_xor(wp, 1);
            wp += __shfl_xor(wp, 2);
        }
        __syncthreads();

        // S2: r_new
        if (tid < 4 * NR && (tid & 3) == 0) {
            int i = tid >> 2;
            float Itot;
            if (i < NM) {
                Itot = Imbon_sh[i];
            } else if (i < NM + NF) {
                float e0 = r_ext[((size_t)b * NE + 0) * TT + t];
                float e1 = r_ext[((size_t)b * NE + 1) * TT + t];
                Itot = e0 * W_ext[(i - NM) * NE + 0] + e1 * W_ext[(i - NM) * NE + 1];
            } else {
                Itot = 0.f;
            }
            float act = fmaxf(wp + bias_sh[i] + Itot, 0.f);
            float rn  = rsh[i] + (act - rsh[i]) * dtr;
            rnew_sh[i] = rn;
            out[R_OFF + ((size_t)(t + 1) * NB + b) * NR + i] = rn;
        }
        __syncthreads();

        // S3: dan traces, r copy, readout
        if (tid < ND) {
            float rd = rnew_sh[NR - ND + tid];
            rdan_sh[tid] = rd;
            rbdan_sh[tid] += (rd - rbdan_sh[tid]) * dtw;
        }
        if (tid >= 128 && tid < 128 + NR) rsh[tid - 128] = rnew_sh[tid - 128];
        if (tid == 64) {
            float ro = 0.f;
            #pragma unroll
            for (int m = 0; m < NM; ++m) ro += rnew_sh[m] * Wro_sh[m];
            out[RO_OFF + (size_t)(t + 1) * NB + b] = ro;
        }
        __syncthreads();

        // S4: plasticity update + history stores
        float a = rbdan_sh[d];
        float c = rdan_sh[d];
        const size_t slab  = (size_t)(t + 1) * (NB * NM * NK);
        const size_t baseW  = W_OFF  + slab + rowbase;
        const size_t baseWT = WT_OFF + slab + rowbase;
        #pragma unroll
        for (int j = 0; j < 7; ++j) {
            int k0 = 4 * kg + 128 * j;
            if (k0 < NK) {
                float4 v4 = *(const float4*)&vsh[k0];
                wtv[j].x += dt * (a * uv[j].x - c * v4.x);
                wtv[j].y += dt * (a * uv[j].y - c * v4.y);
                wtv[j].z += dt * (a * uv[j].z - c * v4.z);
                wtv[j].w += dt * (a * uv[j].w - c * v4.w);
                Wv[j].x = fminf(fmaxf(Wv[j].x + (wtv[j].x - Wv[j].x) * dtw, 0.f), 0.05f);
                Wv[j].y = fminf(fmaxf(Wv[j].y + (wtv[j].y - Wv[j].y) * dtw, 0.f), 0.05f);
                Wv[j].z = fminf(fmaxf(Wv[j].z + (wtv[j].z - Wv[j].z) * dtw, 0.f), 0.05f);
                Wv[j].w = fminf(fmaxf(Wv[j].w + (wtv[j].w - Wv[j].w) * dtw, 0.f), 0.05f);
                *(float4*)(out + baseW  + k0) = Wv[j];
                *(float4*)(out + baseWT + k0) = wtv[j];
            }
        }
        __syncthreads();  // protect vsh/rkc_sh against next S0
    }
}

extern "C" void kernel_launch(void* const* d_in, const int* in_sizes, int n_in,
                              void* d_out, int out_size, void* d_ws, size_t ws_size,
                              hipStream_t stream) {
    const float* r_kc      = (const float*)d_in[0];
    const float* r_ext     = (const float*)d_in[1];
    const float* timev     = (const float*)d_in[2];
    const float* W_kc0     = (const float*)d_in[3];
    const float* wt0       = (const float*)d_in[4];
    const float* W_recur   = (const float*)d_in[5];
    const float* W_readout = (const float*)d_in[6];
    const float* bias      = (const float*)d_in[7];
    const float* W_ext     = (const float*)d_in[8];
    float* out = (float*)d_out;

    rnn_step_kernel<<<dim3(NB), dim3(640), 0, stream>>>(
        r_kc, r_ext, timev, W_kc0, wt0, W_recur, W_readout, bias, W_ext, out);
}